// Round 10
// baseline (222.340 us; speedup 1.0000x reference)
//
#include <hip/hip_runtime.h>
#include <hip/hip_bf16.h>

// Shapes: B=128, C=1000, D=300, L=40, H=100
// Workspace layout (BYTE offsets, 16B-aligned):
#define OFF_Y23     0          // y23    [1024] f32        4096
#define OFF_BDP     4096       // bdPad  [112]  f32        448
#define OFF_WJP     4544       // WjPad  [112]  f32        448
#define OFF_BCP     4992       // bcPad  [320]  f32        1280
#define OFF_BMRP    6272       // bmrPad [112]  f32        448
#define OFF_BMCP    6720       // bmcPad [112]  f32        448
#define OFF_WALLT   7168       // WallT  [1920][320] bf16  1228800
#define OFF_PBF     1235968    // Pbf    [5120][1920] bf16 19660800
#define OFF_FUBF    20896768   // fubf   [128][320] bf16   81920
#define OFF_FUBFT   20978688   // fubfT  [320][128] bf16   81920
#define OFF_CATSV   21060608   // catsv  [1024][640] bf16  1310720
#define OFF_WCPK    22371328   // WcPk   [320][640] bf16   409600
#define OFF_CANDBF  22780928   // candbf [1024][320] bf16  655360
#define OFF_WDFRAG  23436288   // WdFrag  [10][448][8] bf16 71680
#define OFF_WMRFRAG 23507968   // WmrFrag [10][448][8] bf16 71680
#define OFF_WMCFRAG 23579648   // WmcFrag [10][448][8] bf16 71680
#define OFF_SYSB    23651328   // sysB   [128][320] bf16   81920
#define OFF_CONFSB  23733248   // confsB [128][320] bf16   81920
#define OFF_CONFVB  23815168   // confvB [128][320] bf16   81920
#define OFF_PRBF    23897088   // Prbf   [1024][128] bf16  262144
#define OFF_PCBF    24159232   // Pcbf   [1024][128] bf16  262144
#define OFF_SMRBF   24421376   // smrbf  [1024][320] bf16  655360
#define OFF_SMCBF   25076736   // smcbf  [1024][320] bf16  655360
#define OFF_XBF     25732096   // Xbf    [5120][320] bf16  3276800
#define OFF_CNT     29008896   // cnt    [2] u32 (phase counters) 16
// total ~27.7 MB

typedef short bf16x8_t __attribute__((ext_vector_type(8)));
typedef float f32x4_t  __attribute__((ext_vector_type(4)));

__device__ __forceinline__ float sigmoidf_fast(float x) {
    return __builtin_amdgcn_rcpf(1.0f + __expf(-x));
}
__device__ __forceinline__ unsigned short f2bf(float x) {
    unsigned int u = __float_as_uint(x);
    unsigned int r = (u + 0x7FFFu + ((u >> 16) & 1u)) >> 16;
    return (unsigned short)r;
}
__device__ __forceinline__ float bf2f(unsigned short h) {
    return __uint_as_float(((unsigned int)h) << 16);
}

// ---------------------------------------------------------------- K0: pack
__global__ __launch_bounds__(256) void pack_kernel(const float* __restrict__ w1,
        const float* __restrict__ w2, const float* __restrict__ w3,
        const float* __restrict__ Wc, const float* __restrict__ Wd,
        const float* __restrict__ Wmr, const float* __restrict__ Wmc,
        const float* __restrict__ sys, const float* __restrict__ confs,
        const float* __restrict__ confv, const float* __restrict__ bd,
        const float* __restrict__ Wj, const float* __restrict__ bmr,
        const float* __restrict__ bmc, const float* __restrict__ bc,
        const float* __restrict__ slot, const float* __restrict__ value,
        const float* __restrict__ utt,
        unsigned short* __restrict__ WallTbf, unsigned short* __restrict__ WdFrag,
        unsigned short* __restrict__ WmrFrag, unsigned short* __restrict__ WmcFrag,
        float* __restrict__ bdPad, float* __restrict__ WjPad,
        float* __restrict__ bmrPad, float* __restrict__ bmcPad,
        float* __restrict__ bcPad,
        unsigned short* __restrict__ sysB, unsigned short* __restrict__ confsB,
        unsigned short* __restrict__ confvB, unsigned short* __restrict__ catsv,
        unsigned short* __restrict__ WcPk, unsigned short* __restrict__ Xbf,
        unsigned int* __restrict__ cnt) {
    int t = blockIdx.x * 256 + threadIdx.x;
    union { unsigned short u[8]; uint4 q; } o;
    if (t < 76800) {
        int i8 = t * 8;
        int tap = i8 / 102400;
        int rem = i8 - tap * 102400;
        int f = rem / 320, k0 = rem % 320;
        #pragma unroll
        for (int e = 0; e < 8; e++) {
            int k = k0 + e;
            float v = 0.0f;
            if (f < 300 && k < 300) {
                int fd = f * 300 + k;
                v = (tap == 0) ? w1[fd] : (tap == 1) ? w2[fd * 2]
                  : (tap == 2) ? w2[fd * 2 + 1] : w3[fd * 3 + (tap - 3)];
            }
            o.u[e] = f2bf(v);
        }
        *(uint4*)(WallTbf + i8) = o.q;
    } else if (t < 90240) {
        int ent = t - 76800;
        int mat = ent / 4480;
        int le = ent - mat * 4480;
        const float* W = (mat == 0) ? Wd : ((mat == 1) ? Wmr : Wmc);
        unsigned short* dst = (mat == 0) ? WdFrag : ((mat == 1) ? WmrFrag : WmcFrag);
        int kt = le / 448;
        int r = le - kt * 448;
        int ni = r >> 6, lane = r & 63;
        int j = ni * 16 + (lane & 15);
        int kb = kt * 32 + (lane >> 4) * 8;
        #pragma unroll
        for (int e = 0; e < 8; e++) {
            int k = kb + e;
            o.u[e] = f2bf((j < 100 && k < 300) ? W[j * 300 + k] : 0.0f);
        }
        *(uint4*)(dst + le * 8) = o.q;
    } else if (t < 105600) {
        int i8 = (t - 90240) * 8;
        int m = i8 / 40960, r = i8 - m * 40960;
        int bb = r / 320, k0 = r % 320;
        const float* src = (m == 0) ? sys : ((m == 1) ? confs : confv);
        unsigned short* dst = (m == 0) ? sysB : ((m == 1) ? confsB : confvB);
        #pragma unroll
        for (int e = 0; e < 8; e++) {
            int k = k0 + e;
            o.u[e] = f2bf((k < 300) ? src[bb * 300 + k] : 0.0f);
        }
        *(uint4*)(dst + r) = o.q;
    } else if (t < 187520) {
        int i8 = (t - 105600) * 8;
        int c = i8 / 640, k0 = i8 % 640;
        #pragma unroll
        for (int e = 0; e < 8; e++) {
            int k = k0 + e;
            float v = 0.0f;
            if (c < 1000) {
                if (k < 300)                  v = slot[c * 300 + k];
                else if (k >= 320 && k < 620) v = value[c * 300 + (k - 320)];
            }
            o.u[e] = f2bf(v);
        }
        *(uint4*)(catsv + i8) = o.q;
    } else if (t < 213120) {
        int i8 = (t - 187520) * 8;
        int f = i8 / 640, k0 = i8 % 640;
        #pragma unroll
        for (int e = 0; e < 8; e++) {
            int k = k0 + e;
            float v = 0.0f;
            if (f < 300) {
                if (k < 300)                  v = Wc[f * 600 + k];
                else if (k >= 320 && k < 620) v = Wc[f * 600 + 300 + (k - 320)];
            }
            o.u[e] = f2bf(v);
        }
        *(uint4*)(WcPk + i8) = o.q;
    } else if (t < 417920) {
        int i8 = (t - 213120) * 8;
        int m = i8 / 320, k0 = i8 % 320;
        if (k0 + 8 <= 300) {
            float4 a = *(const float4*)(utt + m * 300 + k0);
            float4 b = *(const float4*)(utt + m * 300 + k0 + 4);
            o.u[0] = f2bf(a.x); o.u[1] = f2bf(a.y); o.u[2] = f2bf(a.z); o.u[3] = f2bf(a.w);
            o.u[4] = f2bf(b.x); o.u[5] = f2bf(b.y); o.u[6] = f2bf(b.z); o.u[7] = f2bf(b.w);
        } else {
            #pragma unroll
            for (int e = 0; e < 8; e++) {
                int k = k0 + e;
                o.u[e] = f2bf((k < 300) ? utt[m * 300 + k] : 0.0f);
            }
        }
        *(uint4*)(Xbf + i8) = o.q;
    } else if (t < 418688) {
        int j = t - 417920;
        if (j < 112)      bdPad[j] = (j < 100) ? bd[j] : 0.0f;
        else if (j < 224) { int jj = j - 112; WjPad[jj]  = (jj < 100) ? Wj[jj]  : 0.0f; }
        else if (j < 336) { int jj = j - 224; bmrPad[jj] = (jj < 100) ? bmr[jj] : 0.0f; }
        else if (j < 448) { int jj = j - 336; bmcPad[jj] = (jj < 100) ? bmc[jj] : 0.0f; }
        else              { int jj = j - 448; bcPad[jj]  = (jj < 300) ? bc[jj]  : 0.0f; }
    } else if (t < 418690) {
        cnt[t - 418688] = 0u;        // phase counters for tail kernel
    }
}

// --------------- K1 (merged): cand (80) + pgate (32) + gemm1 (1200, XCD-swizzled)
__global__ __launch_bounds__(256, 4) void early_kernel(
        const unsigned short* __restrict__ Xbf, const unsigned short* __restrict__ WallTbf,
        unsigned short* __restrict__ Pbf,
        const unsigned short* __restrict__ catsv, const unsigned short* __restrict__ WcPk,
        const float* __restrict__ bcPad, unsigned short* __restrict__ candbf,
        const unsigned short* __restrict__ sysB, const unsigned short* __restrict__ confsB,
        const unsigned short* __restrict__ confvB,
        unsigned short* __restrict__ Prbf, unsigned short* __restrict__ Pcbf) {
    __shared__ __attribute__((aligned(16))) char smem[25600];
    const int bid = blockIdx.x;
    const int tid = threadIdx.x;
    const int lane = tid & 63, w = tid >> 6;
    const int ln = lane & 15, lq = lane >> 4;

    if (bid >= 112) {
        short* As = (short*)smem;               // [64][40]
        short* Bs = (short*)(smem + 5120);      // [128][40]
        const int g = bid - 112;
        const int xcd = g & 7;
        const int idx2 = g >> 3;                 // 0..149
        const int m0 = (xcd * 10 + idx2 / 15) * 64;
        const int n0 = (idx2 % 15) * 128;
        const int arow = tid >> 2, aq = tid & 3;
        f32x4_t acc[4][2];
        #pragma unroll
        for (int i = 0; i < 4; i++)
            #pragma unroll
            for (int j = 0; j < 2; j++) acc[i][j] = (f32x4_t){0.f, 0.f, 0.f, 0.f};

        const unsigned short* aSrc  = Xbf + (m0 + arow) * 320 + aq * 8;
        const unsigned short* bSrc0 = WallTbf + (n0 + arow) * 320 + aq * 8;
        const unsigned short* bSrc1 = WallTbf + (n0 + 64 + arow) * 320 + aq * 8;
        uint4 pa  = *(const uint4*)(aSrc);
        uint4 pb0 = *(const uint4*)(bSrc0);
        uint4 pb1 = *(const uint4*)(bSrc1);
        *(uint4*)(&As[arow * 40 + aq * 8]) = pa;
        *(uint4*)(&Bs[arow * 40 + aq * 8]) = pb0;
        *(uint4*)(&Bs[(64 + arow) * 40 + aq * 8]) = pb1;
        __syncthreads();

        #pragma unroll 1
        for (int kt = 0; kt < 10; kt++) {
            if (kt < 9) {
                int kk2 = (kt + 1) * 32;
                pa  = *(const uint4*)(aSrc + kk2);
                pb0 = *(const uint4*)(bSrc0 + kk2);
                pb1 = *(const uint4*)(bSrc1 + kk2);
            }
            bf16x8_t a[4], b[2];
            #pragma unroll
            for (int mi = 0; mi < 4; mi++)
                a[mi] = *(const bf16x8_t*)(&As[(mi * 16 + ln) * 40 + lq * 8]);
            #pragma unroll
            for (int ni = 0; ni < 2; ni++)
                b[ni] = *(const bf16x8_t*)(&Bs[(w * 32 + ni * 16 + ln) * 40 + lq * 8]);
            #pragma unroll
            for (int mi = 0; mi < 4; mi++)
                #pragma unroll
                for (int ni = 0; ni < 2; ni++)
                    acc[mi][ni] = __builtin_amdgcn_mfma_f32_16x16x32_bf16(a[mi], b[ni], acc[mi][ni], 0, 0, 0);
            if (kt < 9) {
                __syncthreads();
                *(uint4*)(&As[arow * 40 + aq * 8]) = pa;
                *(uint4*)(&Bs[arow * 40 + aq * 8]) = pb0;
                *(uint4*)(&Bs[(64 + arow) * 40 + aq * 8]) = pb1;
                __syncthreads();
            }
        }
        #pragma unroll
        for (int mi = 0; mi < 4; mi++) {
            #pragma unroll
            for (int ni = 0; ni < 2; ni++) {
                int col = n0 + w * 32 + ni * 16 + ln;
                #pragma unroll
                for (int reg = 0; reg < 4; reg++) {
                    int row = m0 + mi * 16 + lq * 4 + reg;
                    Pbf[row * 1920 + col] = f2bf(acc[mi][ni][reg]);
                }
            }
        }
    } else if (bid < 80) {
        short* As = (short*)smem;               // [64][40]
        short* Bs = (short*)(smem + 5120);      // [64][40]
        const int m0 = (bid / 5) * 64, n0 = (bid % 5) * 64;
        const int wr = w & 1, wc = w >> 1;
        f32x4_t acc[2][2];
        #pragma unroll
        for (int i = 0; i < 2; i++)
            #pragma unroll
            for (int j = 0; j < 2; j++) acc[i][j] = (f32x4_t){0.f, 0.f, 0.f, 0.f};
        const int srow = tid >> 2, sq = tid & 3;
        for (int kk = 0; kk < 640; kk += 32) {
            *(uint4*)(&As[srow * 40 + sq * 8]) = *(const uint4*)(catsv + (m0 + srow) * 640 + kk + sq * 8);
            *(uint4*)(&Bs[srow * 40 + sq * 8]) = *(const uint4*)(WcPk  + (n0 + srow) * 640 + kk + sq * 8);
            __syncthreads();
            bf16x8_t a[2], b[2];
            #pragma unroll
            for (int mi = 0; mi < 2; mi++)
                a[mi] = *(const bf16x8_t*)(&As[(wr * 32 + mi * 16 + ln) * 40 + lq * 8]);
            #pragma unroll
            for (int ni = 0; ni < 2; ni++)
                b[ni] = *(const bf16x8_t*)(&Bs[(wc * 32 + ni * 16 + ln) * 40 + lq * 8]);
            #pragma unroll
            for (int mi = 0; mi < 2; mi++)
                #pragma unroll
                for (int ni = 0; ni < 2; ni++)
                    acc[mi][ni] = __builtin_amdgcn_mfma_f32_16x16x32_bf16(a[mi], b[ni], acc[mi][ni], 0, 0, 0);
            __syncthreads();
        }
        #pragma unroll
        for (int mi = 0; mi < 2; mi++) {
            #pragma unroll
            for (int ni = 0; ni < 2; ni++) {
                int n = n0 + wc * 32 + ni * 16 + ln;
                float bcv = bcPad[n];
                #pragma unroll
                for (int reg = 0; reg < 4; reg++) {
                    int cr = m0 + wr * 32 + mi * 16 + lq * 4 + reg;
                    candbf[cr * 320 + n] = f2bf(sigmoidf_fast(acc[mi][ni][reg] + bcv));
                }
            }
        }
    } else {
        short* As0 = (short*)smem;              // [64][40]
        short* As1 = (short*)(smem + 5120);
        short* Bs0 = (short*)(smem + 10240);    // [64][40] x3
        short* Bs1 = (short*)(smem + 15360);
        short* Bs2 = (short*)(smem + 20480);
        const int pid = bid - 80;
        const int c0 = (pid >> 1) * 64;
        const int bh = (pid & 1) * 64;
        f32x4_t accR[4], accS[4], accV[4];
        #pragma unroll
        for (int i = 0; i < 4; i++) {
            accR[i] = (f32x4_t){0.f, 0.f, 0.f, 0.f};
            accS[i] = (f32x4_t){0.f, 0.f, 0.f, 0.f};
            accV[i] = (f32x4_t){0.f, 0.f, 0.f, 0.f};
        }
        for (int kk = 0; kk < 320; kk += 32) {
            #pragma unroll
            for (int i = tid; i < 512; i += 256) {
                int mat = i >> 8, r2 = i & 255;
                int row = r2 >> 2, q = r2 & 3;
                short* dst = mat ? As1 : As0;
                *(uint4*)(&dst[row * 40 + q * 8]) =
                    *(const uint4*)(catsv + (c0 + row) * 640 + mat * 320 + kk + q * 8);
            }
            #pragma unroll
            for (int i = tid; i < 768; i += 256) {
                int mat = i >> 8, r2 = i & 255;
                int row = r2 >> 2, q = r2 & 3;
                const unsigned short* src = (mat == 0) ? sysB : ((mat == 1) ? confsB : confvB);
                short* dst = (mat == 0) ? Bs0 : ((mat == 1) ? Bs1 : Bs2);
                *(uint4*)(&dst[row * 40 + q * 8]) =
                    *(const uint4*)(src + (bh + row) * 320 + kk + q * 8);
            }
            __syncthreads();
            bf16x8_t aS = *(const bf16x8_t*)(&As0[(w * 16 + ln) * 40 + lq * 8]);
            bf16x8_t aV = *(const bf16x8_t*)(&As1[(w * 16 + ln) * 40 + lq * 8]);
            #pragma unroll
            for (int ni = 0; ni < 4; ni++) {
                bf16x8_t bR = *(const bf16x8_t*)(&Bs0[(ni * 16 + ln) * 40 + lq * 8]);
                bf16x8_t bS = *(const bf16x8_t*)(&Bs1[(ni * 16 + ln) * 40 + lq * 8]);
                bf16x8_t bV = *(const bf16x8_t*)(&Bs2[(ni * 16 + ln) * 40 + lq * 8]);
                accR[ni] = __builtin_amdgcn_mfma_f32_16x16x32_bf16(aS, bR, accR[ni], 0, 0, 0);
                accS[ni] = __builtin_amdgcn_mfma_f32_16x16x32_bf16(aS, bS, accS[ni], 0, 0, 0);
                accV[ni] = __builtin_amdgcn_mfma_f32_16x16x32_bf16(aV, bV, accV[ni], 0, 0, 0);
            }
            __syncthreads();
        }
        #pragma unroll
        for (int ni = 0; ni < 4; ni++) {
            int b = bh + ni * 16 + ln;
            #pragma unroll
            for (int reg = 0; reg < 4; reg++) {
                int c = c0 + w * 16 + lq * 4 + reg;
                Prbf[c * 128 + b] = f2bf(accR[ni][reg]);
                Pcbf[c * 128 + b] = f2bf(accS[ni][reg] * accV[ni][reg]);
            }
        }
    }
}

// ------- K2 (fused tail): combine (160) -> mgate (80) -> ygate (16), 256 blocks
// All 256 blocks are co-resident (<= 1 block/CU), so spin-wait phases are safe.
__global__ __launch_bounds__(256) void tail_kernel(const unsigned short* __restrict__ Pbf,
        const float* __restrict__ b1, const float* __restrict__ b2,
        const float* __restrict__ b3, unsigned short* __restrict__ fubf,
        unsigned short* __restrict__ fubfT,
        const unsigned short* __restrict__ Prbf, const unsigned short* __restrict__ Pcbf,
        unsigned short* __restrict__ smrbf, unsigned short* __restrict__ smcbf,
        const unsigned short* __restrict__ WmrFrag, const unsigned short* __restrict__ WmcFrag,
        const float* __restrict__ bmrPad, const float* __restrict__ bmcPad,
        const float* __restrict__ WjPad, const float* __restrict__ bj,
        float* __restrict__ y23, unsigned int* __restrict__ cnt) {
    __shared__ __attribute__((aligned(16))) char smem[24576];
    const int bid = blockIdx.x;
    const int tid = threadIdx.x;
    const int lane = tid & 63, w = tid >> 6;
    const int ln = lane & 15, lq = lane >> 4;

    if (bid < 160) {
        // ---- phase 0: tap-combine + relu + maxpool -> fubf/fubfT
        int g = bid * 256 + tid;                 // 0..40959
        int b = g / 320, f = g % 320;
        if (f >= 300) {
            fubf[b * 320 + f] = 0; fubfT[f * 128 + b] = 0;
        } else {
            const unsigned short* base = Pbf + (size_t)b * 40 * 1920;
            float m1 = -1e30f, m2 = -1e30f, m3 = -1e30f;
            float p1prev = 0.f, p3prev = 0.f, p3prev2 = 0.f, p4prev = 0.f;
            for (int t = 0; t < 40; ++t) {
                const unsigned short* r = base + t * 1920;
                float p0 = bf2f(r[f]);
                float p1 = bf2f(r[320 + f]);
                float p2 = bf2f(r[640 + f]);
                float p3 = bf2f(r[960 + f]);
                float p4 = bf2f(r[1280 + f]);
                float p5 = bf2f(r[1600 + f]);
                m1 = fmaxf(m1, p0);
                if (t >= 1) m2 = fmaxf(m2, p1prev + p2);
                if (t >= 2) m3 = fmaxf(m3, p3prev2 + p4prev + p5);
                p3prev2 = p3prev; p3prev = p3; p4prev = p4; p1prev = p1;
            }
            float r = fmaxf(m1 + b1[f], 0.f) + fmaxf(m2 + b2[f], 0.f) + fmaxf(m3 + b3[f], 0.f);
            unsigned short rb = f2bf(r);
            fubf[b * 320 + f]  = rb;
            fubfT[f * 128 + b] = rb;
        }
        __threadfence();
        __syncthreads();
        if (tid == 0) atomicAdd(&cnt[0], 1u);
    } else if (bid < 240) {
        // ---- phase 1: mgate (wait for all combine blocks)
        if (tid == 0) {
            while (__hip_atomic_load(&cnt[0], __ATOMIC_RELAXED, __HIP_MEMORY_SCOPE_AGENT) < 160u)
                __builtin_amdgcn_s_sleep(8);
            __threadfence();
        }
        __syncthreads();
        short* As0 = (short*)smem;               // [64][40]
        short* As1 = (short*)(smem + 5120);
        short* Bs  = (short*)(smem + 10240);     // [64][40]
        const int pid = bid - 160;
        const int m0 = (pid / 5) * 64, n0 = (pid % 5) * 64;
        const int wr = w & 1, wc = w >> 1;
        f32x4_t accR[2][2], accC[2][2];
        #pragma unroll
        for (int i = 0; i < 2; i++)
            #pragma unroll
            for (int j = 0; j < 2; j++) {
                accR[i][j] = (f32x4_t){0.f, 0.f, 0.f, 0.f};
                accC[i][j] = (f32x4_t){0.f, 0.f, 0.f, 0.f};
            }
        for (int kk = 0; kk < 128; kk += 32) {
            #pragma unroll
            for (int i = tid; i < 512; i += 256) {
                int mat = i >> 8, r2 = i & 255;
                int row = r2 >> 2, q = r2 & 3;
                const unsigned short* src = mat ? Pcbf : Prbf;
                short* dst = mat ? As1 : As0;
                *(uint4*)(&dst[row * 40 + q * 8]) =
                    *(const uint4*)(src + (m0 + row) * 128 + kk + q * 8);
            }
            {
                int row = tid >> 2, q = tid & 3;
                *(uint4*)(&Bs[row * 40 + q * 8]) =
                    *(const uint4*)(fubfT + (n0 + row) * 128 + kk + q * 8);
            }
            __syncthreads();
            bf16x8_t aR[2], aC[2], b[2];
            #pragma unroll
            for (int mi = 0; mi < 2; mi++) {
                aR[mi] = *(const bf16x8_t*)(&As0[(wr * 32 + mi * 16 + ln) * 40 + lq * 8]);
                aC[mi] = *(const bf16x8_t*)(&As1[(wr * 32 + mi * 16 + ln) * 40 + lq * 8]);
            }
            #pragma unroll
            for (int ni = 0; ni < 2; ni++)
                b[ni] = *(const bf16x8_t*)(&Bs[(wc * 32 + ni * 16 + ln) * 40 + lq * 8]);
            #pragma unroll
            for (int mi = 0; mi < 2; mi++)
                #pragma unroll
                for (int ni = 0; ni < 2; ni++) {
                    accR[mi][ni] = __builtin_amdgcn_mfma_f32_16x16x32_bf16(aR[mi], b[ni], accR[mi][ni], 0, 0, 0);
                    accC[mi][ni] = __builtin_amdgcn_mfma_f32_16x16x32_bf16(aC[mi], b[ni], accC[mi][ni], 0, 0, 0);
                }
            __syncthreads();
        }
        #pragma unroll
        for (int mi = 0; mi < 2; mi++) {
            #pragma unroll
            for (int ni = 0; ni < 2; ni++) {
                int f = n0 + wc * 32 + ni * 16 + ln;
                #pragma unroll
                for (int reg = 0; reg < 4; reg++) {
                    int c = m0 + wr * 32 + mi * 16 + lq * 4 + reg;
                    smrbf[c * 320 + f] = f2bf(sigmoidf_fast(accR[mi][ni][reg]));
                    smcbf[c * 320 + f] = f2bf(sigmoidf_fast(accC[mi][ni][reg]));
                }
            }
        }
        __threadfence();
        __syncthreads();
        if (tid == 0) atomicAdd(&cnt[1], 1u);
    } else {
        // ---- phase 2: ygate (wait for all mgate blocks)
        if (tid == 0) {
            while (__hip_atomic_load(&cnt[1], __ATOMIC_RELAXED, __HIP_MEMORY_SCOPE_AGENT) < 80u)
                __builtin_amdgcn_s_sleep(8);
            __threadfence();
        }
        __syncthreads();
        short* As0 = (short*)smem;               // [64][40]
        short* As1 = (short*)(smem + 5120);
        short* Bs0 = (short*)(smem + 10240);     // [448][8] x2
        short* Bs1 = (short*)(smem + 17408);
        const int c0 = (bid - 240) * 64;
        f32x4_t accR[7], accC[7];
        #pragma unroll
        for (int i = 0; i < 7; i++) {
            accR[i] = (f32x4_t){0.f, 0.f, 0.f, 0.f};
            accC[i] = (f32x4_t){0.f, 0.f, 0.f, 0.f};
        }
        for (int kt = 0; kt < 10; kt++) {
            int kk = kt * 32;
            #pragma unroll
            for (int i = tid; i < 512; i += 256) {
                int mat = i >> 8, r2 = i & 255;
                int row = r2 >> 2, q = r2 & 3;
                const unsigned short* src = mat ? smcbf : smrbf;
                short* dst = mat ? As1 : As0;
                *(uint4*)(&dst[row * 40 + q * 8]) =
                    *(const uint4*)(src + (c0 + row) * 320 + kk + q * 8);
            }
            #pragma unroll
            for (int i = tid; i < 896; i += 256) {
                int mat = i / 448, j = i - mat * 448;
                const uint4* s = (const uint4*)((mat ? WmcFrag : WmrFrag) + kt * 3584);
                ((uint4*)(mat ? Bs1 : Bs0))[j] = s[j];
            }
            __syncthreads();
            bf16x8_t aR = *(const bf16x8_t*)(&As0[(w * 16 + ln) * 40 + lq * 8]);
            bf16x8_t aC = *(const bf16x8_t*)(&As1[(w * 16 + ln) * 40 + lq * 8]);
            #pragma unroll
            for (int ni = 0; ni < 7; ni++) {
                bf16x8_t bR = *(const bf16x8_t*)(&Bs0[(ni * 64 + lane) * 8]);
                bf16x8_t bC = *(const bf16x8_t*)(&Bs1[(ni * 64 + lane) * 8]);
                accR[ni] = __builtin_amdgcn_mfma_f32_16x16x32_bf16(aR, bR, accR[ni], 0, 0, 0);
                accC[ni] = __builtin_amdgcn_mfma_f32_16x16x32_bf16(aC, bC, accC[ni], 0, 0, 0);
            }
            __syncthreads();
        }
        float psum[4] = {0.f, 0.f, 0.f, 0.f};
        #pragma unroll
        for (int ni = 0; ni < 7; ni++) {
            int n = ni * 16 + ln;
            float wj = WjPad[n], br = bmrPad[n], bcv = bmcPad[n];
            #pragma unroll
            for (int reg = 0; reg < 4; reg++) {
                float hr = sigmoidf_fast(accR[ni][reg] + br);
                float hc = sigmoidf_fast(accC[ni][reg] + bcv);
                psum[reg] += (hr + hc) * wj;
            }
        }
        #pragma unroll
        for (int reg = 0; reg < 4; reg++) {
            float v = psum[reg];
            v += __shfl_xor(v, 1);
            v += __shfl_xor(v, 2);
            v += __shfl_xor(v, 4);
            v += __shfl_xor(v, 8);
            if (ln == 0) {
                int c = c0 + w * 16 + lq * 4 + reg;
                y23[c] = v + 2.0f * bj[0];
            }
        }
    }
}

// --------------------- K3: fused main MLP GEMM (per-c), register A-frag gen
__global__ __launch_bounds__(256) void gemm2_kernel(const unsigned short* __restrict__ candbf,
        const unsigned short* __restrict__ fubf, const unsigned short* __restrict__ WdFrag,
        const float* __restrict__ bdPad, const float* __restrict__ WjPad,
        const float* __restrict__ bj, const float* __restrict__ y23,
        const float* __restrict__ ypast, float* __restrict__ out) {
    __shared__ __attribute__((aligned(16))) short Bs[2][3584];
    __shared__ float bdS[112], WjS[112], ybuf[128];
    const int c = blockIdx.x;
    const int tid = threadIdx.x;
    const int lane = tid & 63, w = tid >> 6;
    const int ln = lane & 15, lq = lane >> 4;
    if (tid < 112) { bdS[tid] = bdPad[tid]; WjS[tid] = WjPad[tid]; }

    const unsigned short* candRow = candbf + c * 320;
    const unsigned short* fuR0 = fubf + (w * 32 + ln) * 320;
    const unsigned short* fuR1 = fuR0 + 16 * 320;

    f32x4_t acc[2][7];
    #pragma unroll
    for (int mi = 0; mi < 2; mi++)
        #pragma unroll
        for (int ni = 0; ni < 7; ni++) acc[mi][ni] = (f32x4_t){0.f, 0.f, 0.f, 0.f};

    {
        const uint4* src = (const uint4*)(WdFrag);
        uint4* dst = (uint4*)&Bs[0][0];
        dst[tid] = src[tid];
        if (tid < 192) dst[tid + 256] = src[tid + 256];
    }
    __syncthreads();

    #pragma unroll
    for (int kt = 0; kt < 10; kt++) {
        if (kt < 9) {
            const uint4* src = (const uint4*)(WdFrag + (kt + 1) * 3584);
            uint4* dst = (uint4*)&Bs[(kt + 1) & 1][0];
            dst[tid] = src[tid];
            if (tid < 192) dst[tid + 256] = src[tid + 256];
        }
        const int k0 = kt * 32 + lq * 8;
        bf16x8_t cf  = *(const bf16x8_t*)(candRow + k0);
        bf16x8_t f0v = *(const bf16x8_t*)(fuR0 + k0);
        bf16x8_t f1v = *(const bf16x8_t*)(fuR1 + k0);
        bf16x8_t a0, a1;
        #pragma unroll
        for (int e = 0; e < 8; e += 2) {
            float cv0 = bf2f((unsigned short)cf[e]);
            float cv1 = bf2f((unsigned short)cf[e + 1]);
            float2 s0 = make_float2(sigmoidf_fast(cv0 * bf2f((unsigned short)f0v[e])),
                                    sigmoidf_fast(cv1 * bf2f((unsigned short)f0v[e + 1])));
            float2 s1 = make_float2(sigmoidf_fast(cv0 * bf2f((unsigned short)f1v[e])),
                                    sigmoidf_fast(cv1 * bf2f((unsigned short)f1v[e + 1])));
            __hip_bfloat162 p0 = __float22bfloat162_rn(s0);
            __hip_bfloat162 p1 = __float22bfloat162_rn(s1);
            ((unsigned int*)&a0)[e >> 1] = *(unsigned int*)&p0;
            ((unsigned int*)&a1)[e >> 1] = *(unsigned int*)&p1;
        }
        #pragma unroll
        for (int ni = 0; ni < 7; ni++) {
            bf16x8_t bfr = *(const bf16x8_t*)(&Bs[kt & 1][(ni * 64 + lane) * 8]);
            acc[0][ni] = __builtin_amdgcn_mfma_f32_16x16x32_bf16(a0, bfr, acc[0][ni], 0, 0, 0);
            acc[1][ni] = __builtin_amdgcn_mfma_f32_16x16x32_bf16(a1, bfr, acc[1][ni], 0, 0, 0);
        }
        __syncthreads();
    }

    float psum[2][4] = {{0.f, 0.f, 0.f, 0.f}, {0.f, 0.f, 0.f, 0.f}};
    #pragma unroll
    for (int mi = 0; mi < 2; mi++) {
        #pragma unroll
        for (int ni = 0; ni < 7; ni++) {
            int n = ni * 16 + ln;
            float bdv = bdS[n], wjv = WjS[n];
            #pragma unroll
            for (int reg = 0; reg < 4; reg++) {
                float h = sigmoidf_fast(acc[mi][ni][reg] + bdv);
                psum[mi][reg] += h * wjv;
            }
        }
    }
    #pragma unroll
    for (int mi = 0; mi < 2; mi++) {
        #pragma unroll
        for (int reg = 0; reg < 4; reg++) {
            float v = psum[mi][reg];
            v += __shfl_xor(v, 1);
            v += __shfl_xor(v, 2);
            v += __shfl_xor(v, 4);
            v += __shfl_xor(v, 8);
            if (ln == 0) ybuf[w * 32 + mi * 16 + lq * 4 + reg] = v;
        }
    }
    __syncthreads();
    if (tid < 128) {
        int b = tid;
        float y1 = ybuf[b] + bj[0];
        out[b * 1000 + c] = 0.5f * (y1 + y23[c]) + 0.5f * ypast[b * 1000 + c];
    }
}

extern "C" void kernel_launch(void* const* d_in, const int* in_sizes, int n_in,
                              void* d_out, int out_size, void* d_ws, size_t ws_size,
                              hipStream_t stream) {
    const float* utt   = (const float*)d_in[0];
    const float* sys   = (const float*)d_in[1];
    const float* confs = (const float*)d_in[2];
    const float* confv = (const float*)d_in[3];
    const float* ypast = (const float*)d_in[4];
    const float* slot  = (const float*)d_in[5];
    const float* value = (const float*)d_in[6];
    const float* Wc    = (const float*)d_in[7];
    const float* bc    = (const float*)d_in[8];
    const float* w1    = (const float*)d_in[9];
    const float* b1    = (const float*)d_in[10];
    const float* w2    = (const float*)d_in[11];
    const float* b2    = (const float*)d_in[12];
    const float* w3    = (const float*)d_in[13];
    const float* b3    = (const float*)d_in[14];
    const float* Wd    = (const float*)d_in[15];
    const float* bd    = (const float*)d_in[16];
    const float* Wmr   = (const float*)d_in[17];
    const float* bmr   = (const float*)d_in[18];
    const float* Wmc   = (const float*)d_in[19];
    const float* bmc   = (const float*)d_in[20];
    const float* Wj    = (const float*)d_in[21];
    const float* bj    = (const float*)d_in[22];

    char* wsb = (char*)d_ws;
    float* y23    = (float*)(wsb + OFF_Y23);
    float* bdPad  = (float*)(wsb + OFF_BDP);
    float* WjPad  = (float*)(wsb + OFF_WJP);
    float* bcPad  = (float*)(wsb + OFF_BCP);
    float* bmrPad = (float*)(wsb + OFF_BMRP);
    float* bmcPad = (float*)(wsb + OFF_BMCP);
    unsigned short* WallTbf = (unsigned short*)(wsb + OFF_WALLT);
    unsigned short* Pbf     = (unsigned short*)(wsb + OFF_PBF);
    unsigned short* fubf    = (unsigned short*)(wsb + OFF_FUBF);
    unsigned short* fubfT   = (unsigned short*)(wsb + OFF_FUBFT);
    unsigned short* catsv   = (unsigned short*)(wsb + OFF_CATSV);
    unsigned short* WcPk    = (unsigned short*)(wsb + OFF_WCPK);
    unsigned short* candbf  = (unsigned short*)(wsb + OFF_CANDBF);
    unsigned short* WdFrag  = (unsigned short*)(wsb + OFF_WDFRAG);
    unsigned short* WmrFrag = (unsigned short*)(wsb + OFF_WMRFRAG);
    unsigned short* WmcFrag = (unsigned short*)(wsb + OFF_WMCFRAG);
    unsigned short* sysB    = (unsigned short*)(wsb + OFF_SYSB);
    unsigned short* confsB  = (unsigned short*)(wsb + OFF_CONFSB);
    unsigned short* confvB  = (unsigned short*)(wsb + OFF_CONFVB);
    unsigned short* Prbf    = (unsigned short*)(wsb + OFF_PRBF);
    unsigned short* Pcbf    = (unsigned short*)(wsb + OFF_PCBF);
    unsigned short* smrbf   = (unsigned short*)(wsb + OFF_SMRBF);
    unsigned short* smcbf   = (unsigned short*)(wsb + OFF_SMCBF);
    unsigned short* Xbf     = (unsigned short*)(wsb + OFF_XBF);
    unsigned int*   cnt     = (unsigned int*)(wsb + OFF_CNT);
    float* out = (float*)d_out;

    pack_kernel<<<1636, 256, 0, stream>>>(w1, w2, w3, Wc, Wd, Wmr, Wmc, sys, confs, confv,
                                          bd, Wj, bmr, bmc, bc, slot, value, utt,
                                          WallTbf, WdFrag, WmrFrag, WmcFrag,
                                          bdPad, WjPad, bmrPad, bmcPad, bcPad,
                                          sysB, confsB, confvB, catsv, WcPk, Xbf, cnt);
    early_kernel<<<1312, 256, 0, stream>>>(Xbf, WallTbf, Pbf,
                                           catsv, WcPk, bcPad, candbf,
                                           sysB, confsB, confvB, Prbf, Pcbf);
    tail_kernel<<<256, 256, 0, stream>>>(Pbf, b1, b2, b3, fubf, fubfT,
                                         Prbf, Pcbf, smrbf, smcbf,
                                         WmrFrag, WmcFrag, bmrPad, bmcPad,
                                         WjPad, bj, y23, cnt);
    gemm2_kernel<<<1000, 256, 0, stream>>>(candbf, fubf, WdFrag, bdPad, WjPad,
                                           bj, y23, ypast, out);
}

// Round 11
// 190.451 us; speedup vs baseline: 1.1674x; 1.1674x over previous
//
#include <hip/hip_runtime.h>
#include <hip/hip_bf16.h>

// Shapes: B=128, C=1000, D=300, L=40, H=100
// Workspace layout (BYTE offsets, 16B-aligned):
#define OFF_Y23     0          // y23    [1024] f32        4096
#define OFF_BDP     4096       // bdPad  [112]  f32        448
#define OFF_WJP     4544       // WjPad  [112]  f32        448
#define OFF_BCP     4992       // bcPad  [320]  f32        1280
#define OFF_BMRP    6272       // bmrPad [112]  f32        448
#define OFF_BMCP    6720       // bmcPad [112]  f32        448
#define OFF_WALLT   7168       // WallT  [1920][320] bf16  1228800
#define OFF_PBF     1235968    // Pbf    [5120][1920] bf16 19660800
#define OFF_FUBF    20896768   // fubf   [128][320] bf16   81920
#define OFF_FUBFT   20978688   // fubfT  [320][128] bf16   81920
#define OFF_CATSV   21060608   // catsv  [1024][640] bf16  1310720
#define OFF_WCPK    22371328   // WcPk   [320][640] bf16   409600
#define OFF_CANDBF  22780928   // candbf [1024][320] bf16  655360
#define OFF_WDFRAG  23436288   // WdFrag  [10][448][8] bf16 71680
#define OFF_WMRFRAG 23507968   // WmrFrag [10][448][8] bf16 71680
#define OFF_WMCFRAG 23579648   // WmcFrag [10][448][8] bf16 71680
#define OFF_SYSB    23651328   // sysB   [128][320] bf16   81920
#define OFF_CONFSB  23733248   // confsB [128][320] bf16   81920
#define OFF_CONFVB  23815168   // confvB [128][320] bf16   81920
#define OFF_PRBF    23897088   // Prbf   [1024][128] bf16  262144
#define OFF_PCBF    24159232   // Pcbf   [1024][128] bf16  262144
#define OFF_SMRBF   24421376   // smrbf  [1024][320] bf16  655360
#define OFF_SMCBF   25076736   // smcbf  [1024][320] bf16  655360
#define OFF_XBF     25732096   // Xbf    [5120][320] bf16  3276800
// total 29,008,896 B ~= 27.7 MB

typedef short bf16x8_t __attribute__((ext_vector_type(8)));
typedef float f32x4_t  __attribute__((ext_vector_type(4)));

__device__ __forceinline__ float sigmoidf_fast(float x) {
    return __builtin_amdgcn_rcpf(1.0f + __expf(-x));
}
__device__ __forceinline__ unsigned short f2bf(float x) {
    unsigned int u = __float_as_uint(x);
    unsigned int r = (u + 0x7FFFu + ((u >> 16) & 1u)) >> 16;
    return (unsigned short)r;
}
__device__ __forceinline__ float bf2f(unsigned short h) {
    return __uint_as_float(((unsigned int)h) << 16);
}

// ---------------------------------------------------------------- K0: pack
// 8 bf16 outputs per thread, uint4 stores.
__global__ __launch_bounds__(256) void pack_kernel(const float* __restrict__ w1,
        const float* __restrict__ w2, const float* __restrict__ w3,
        const float* __restrict__ Wc, const float* __restrict__ Wd,
        const float* __restrict__ Wmr, const float* __restrict__ Wmc,
        const float* __restrict__ sys, const float* __restrict__ confs,
        const float* __restrict__ confv, const float* __restrict__ bd,
        const float* __restrict__ Wj, const float* __restrict__ bmr,
        const float* __restrict__ bmc, const float* __restrict__ bc,
        const float* __restrict__ slot, const float* __restrict__ value,
        const float* __restrict__ utt,
        unsigned short* __restrict__ WallTbf, unsigned short* __restrict__ WdFrag,
        unsigned short* __restrict__ WmrFrag, unsigned short* __restrict__ WmcFrag,
        float* __restrict__ bdPad, float* __restrict__ WjPad,
        float* __restrict__ bmrPad, float* __restrict__ bmcPad,
        float* __restrict__ bcPad,
        unsigned short* __restrict__ sysB, unsigned short* __restrict__ confsB,
        unsigned short* __restrict__ confvB, unsigned short* __restrict__ catsv,
        unsigned short* __restrict__ WcPk, unsigned short* __restrict__ Xbf) {
    int t = blockIdx.x * 256 + threadIdx.x;
    union { unsigned short u[8]; uint4 q; } o;
    if (t < 76800) {
        int i8 = t * 8;
        int tap = i8 / 102400;
        int rem = i8 - tap * 102400;
        int f = rem / 320, k0 = rem % 320;
        #pragma unroll
        for (int e = 0; e < 8; e++) {
            int k = k0 + e;
            float v = 0.0f;
            if (f < 300 && k < 300) {
                int fd = f * 300 + k;
                v = (tap == 0) ? w1[fd] : (tap == 1) ? w2[fd * 2]
                  : (tap == 2) ? w2[fd * 2 + 1] : w3[fd * 3 + (tap - 3)];
            }
            o.u[e] = f2bf(v);
        }
        *(uint4*)(WallTbf + i8) = o.q;
    } else if (t < 90240) {
        int ent = t - 76800;
        int mat = ent / 4480;
        int le = ent - mat * 4480;
        const float* W = (mat == 0) ? Wd : ((mat == 1) ? Wmr : Wmc);
        unsigned short* dst = (mat == 0) ? WdFrag : ((mat == 1) ? WmrFrag : WmcFrag);
        int kt = le / 448;
        int r = le - kt * 448;
        int ni = r >> 6, lane = r & 63;
        int j = ni * 16 + (lane & 15);
        int kb = kt * 32 + (lane >> 4) * 8;
        #pragma unroll
        for (int e = 0; e < 8; e++) {
            int k = kb + e;
            o.u[e] = f2bf((j < 100 && k < 300) ? W[j * 300 + k] : 0.0f);
        }
        *(uint4*)(dst + le * 8) = o.q;
    } else if (t < 105600) {
        int i8 = (t - 90240) * 8;
        int m = i8 / 40960, r = i8 - m * 40960;
        int bb = r / 320, k0 = r % 320;
        const float* src = (m == 0) ? sys : ((m == 1) ? confs : confv);
        unsigned short* dst = (m == 0) ? sysB : ((m == 1) ? confsB : confvB);
        #pragma unroll
        for (int e = 0; e < 8; e++) {
            int k = k0 + e;
            o.u[e] = f2bf((k < 300) ? src[bb * 300 + k] : 0.0f);
        }
        *(uint4*)(dst + r) = o.q;
    } else if (t < 187520) {
        int i8 = (t - 105600) * 8;
        int c = i8 / 640, k0 = i8 % 640;
        #pragma unroll
        for (int e = 0; e < 8; e++) {
            int k = k0 + e;
            float v = 0.0f;
            if (c < 1000) {
                if (k < 300)                  v = slot[c * 300 + k];
                else if (k >= 320 && k < 620) v = value[c * 300 + (k - 320)];
            }
            o.u[e] = f2bf(v);
        }
        *(uint4*)(catsv + i8) = o.q;
    } else if (t < 213120) {
        int i8 = (t - 187520) * 8;
        int f = i8 / 640, k0 = i8 % 640;
        #pragma unroll
        for (int e = 0; e < 8; e++) {
            int k = k0 + e;
            float v = 0.0f;
            if (f < 300) {
                if (k < 300)                  v = Wc[f * 600 + k];
                else if (k >= 320 && k < 620) v = Wc[f * 600 + 300 + (k - 320)];
            }
            o.u[e] = f2bf(v);
        }
        *(uint4*)(WcPk + i8) = o.q;
    } else if (t < 417920) {
        int i8 = (t - 213120) * 8;
        int m = i8 / 320, k0 = i8 % 320;
        if (k0 + 8 <= 300) {
            float4 a = *(const float4*)(utt + m * 300 + k0);
            float4 b = *(const float4*)(utt + m * 300 + k0 + 4);
            o.u[0] = f2bf(a.x); o.u[1] = f2bf(a.y); o.u[2] = f2bf(a.z); o.u[3] = f2bf(a.w);
            o.u[4] = f2bf(b.x); o.u[5] = f2bf(b.y); o.u[6] = f2bf(b.z); o.u[7] = f2bf(b.w);
        } else {
            #pragma unroll
            for (int e = 0; e < 8; e++) {
                int k = k0 + e;
                o.u[e] = f2bf((k < 300) ? utt[m * 300 + k] : 0.0f);
            }
        }
        *(uint4*)(Xbf + i8) = o.q;
    } else if (t < 418688) {
        int j = t - 417920;
        if (j < 112)      bdPad[j] = (j < 100) ? bd[j] : 0.0f;
        else if (j < 224) { int jj = j - 112; WjPad[jj]  = (jj < 100) ? Wj[jj]  : 0.0f; }
        else if (j < 336) { int jj = j - 224; bmrPad[jj] = (jj < 100) ? bmr[jj] : 0.0f; }
        else if (j < 448) { int jj = j - 336; bmcPad[jj] = (jj < 100) ? bmc[jj] : 0.0f; }
        else              { int jj = j - 448; bcPad[jj]  = (jj < 300) ? bc[jj]  : 0.0f; }
    }
}

// --------------- K1 (merged): cand (80) + pgate (32) + gemm1 (1200, XCD-swizzled)
__global__ __launch_bounds__(256, 4) void early_kernel(
        const unsigned short* __restrict__ Xbf, const unsigned short* __restrict__ WallTbf,
        unsigned short* __restrict__ Pbf,
        const unsigned short* __restrict__ catsv, const unsigned short* __restrict__ WcPk,
        const float* __restrict__ bcPad, unsigned short* __restrict__ candbf,
        const unsigned short* __restrict__ sysB, const unsigned short* __restrict__ confsB,
        const unsigned short* __restrict__ confvB,
        unsigned short* __restrict__ Prbf, unsigned short* __restrict__ Pcbf) {
    __shared__ __attribute__((aligned(16))) char smem[25600];
    const int bid = blockIdx.x;
    const int tid = threadIdx.x;
    const int lane = tid & 63, w = tid >> 6;
    const int ln = lane & 15, lq = lane >> 4;

    if (bid >= 112) {
        // ---- conv partials GEMM: 64x128 tile, reg-prefetch pipeline
        short* As = (short*)smem;               // [64][40]
        short* Bs = (short*)(smem + 5120);      // [128][40]
        const int g = bid - 112;
        const int xcd = g & 7;
        const int idx2 = g >> 3;                 // 0..149
        const int m0 = (xcd * 10 + idx2 / 15) * 64;
        const int n0 = (idx2 % 15) * 128;
        const int arow = tid >> 2, aq = tid & 3;
        f32x4_t acc[4][2];
        #pragma unroll
        for (int i = 0; i < 4; i++)
            #pragma unroll
            for (int j = 0; j < 2; j++) acc[i][j] = (f32x4_t){0.f, 0.f, 0.f, 0.f};

        const unsigned short* aSrc  = Xbf + (m0 + arow) * 320 + aq * 8;
        const unsigned short* bSrc0 = WallTbf + (n0 + arow) * 320 + aq * 8;
        const unsigned short* bSrc1 = WallTbf + (n0 + 64 + arow) * 320 + aq * 8;
        uint4 pa  = *(const uint4*)(aSrc);
        uint4 pb0 = *(const uint4*)(bSrc0);
        uint4 pb1 = *(const uint4*)(bSrc1);
        *(uint4*)(&As[arow * 40 + aq * 8]) = pa;
        *(uint4*)(&Bs[arow * 40 + aq * 8]) = pb0;
        *(uint4*)(&Bs[(64 + arow) * 40 + aq * 8]) = pb1;
        __syncthreads();

        #pragma unroll 1
        for (int kt = 0; kt < 10; kt++) {
            if (kt < 9) {
                int kk2 = (kt + 1) * 32;
                pa  = *(const uint4*)(aSrc + kk2);
                pb0 = *(const uint4*)(bSrc0 + kk2);
                pb1 = *(const uint4*)(bSrc1 + kk2);
            }
            bf16x8_t a[4], b[2];
            #pragma unroll
            for (int mi = 0; mi < 4; mi++)
                a[mi] = *(const bf16x8_t*)(&As[(mi * 16 + ln) * 40 + lq * 8]);
            #pragma unroll
            for (int ni = 0; ni < 2; ni++)
                b[ni] = *(const bf16x8_t*)(&Bs[(w * 32 + ni * 16 + ln) * 40 + lq * 8]);
            #pragma unroll
            for (int mi = 0; mi < 4; mi++)
                #pragma unroll
                for (int ni = 0; ni < 2; ni++)
                    acc[mi][ni] = __builtin_amdgcn_mfma_f32_16x16x32_bf16(a[mi], b[ni], acc[mi][ni], 0, 0, 0);
            if (kt < 9) {
                __syncthreads();
                *(uint4*)(&As[arow * 40 + aq * 8]) = pa;
                *(uint4*)(&Bs[arow * 40 + aq * 8]) = pb0;
                *(uint4*)(&Bs[(64 + arow) * 40 + aq * 8]) = pb1;
                __syncthreads();
            }
        }
        #pragma unroll
        for (int mi = 0; mi < 4; mi++) {
            #pragma unroll
            for (int ni = 0; ni < 2; ni++) {
                int col = n0 + w * 32 + ni * 16 + ln;
                #pragma unroll
                for (int reg = 0; reg < 4; reg++) {
                    int row = m0 + mi * 16 + lq * 4 + reg;
                    Pbf[row * 1920 + col] = f2bf(acc[mi][ni][reg]);
                }
            }
        }
    } else if (bid < 80) {
        // ---- candidates GEMM: M=1024, N=320, K=640
        short* As = (short*)smem;               // [64][40]
        short* Bs = (short*)(smem + 5120);      // [64][40]
        const int m0 = (bid / 5) * 64, n0 = (bid % 5) * 64;
        const int wr = w & 1, wc = w >> 1;
        f32x4_t acc[2][2];
        #pragma unroll
        for (int i = 0; i < 2; i++)
            #pragma unroll
            for (int j = 0; j < 2; j++) acc[i][j] = (f32x4_t){0.f, 0.f, 0.f, 0.f};
        const int srow = tid >> 2, sq = tid & 3;
        for (int kk = 0; kk < 640; kk += 32) {
            *(uint4*)(&As[srow * 40 + sq * 8]) = *(const uint4*)(catsv + (m0 + srow) * 640 + kk + sq * 8);
            *(uint4*)(&Bs[srow * 40 + sq * 8]) = *(const uint4*)(WcPk  + (n0 + srow) * 640 + kk + sq * 8);
            __syncthreads();
            bf16x8_t a[2], b[2];
            #pragma unroll
            for (int mi = 0; mi < 2; mi++)
                a[mi] = *(const bf16x8_t*)(&As[(wr * 32 + mi * 16 + ln) * 40 + lq * 8]);
            #pragma unroll
            for (int ni = 0; ni < 2; ni++)
                b[ni] = *(const bf16x8_t*)(&Bs[(wc * 32 + ni * 16 + ln) * 40 + lq * 8]);
            #pragma unroll
            for (int mi = 0; mi < 2; mi++)
                #pragma unroll
                for (int ni = 0; ni < 2; ni++)
                    acc[mi][ni] = __builtin_amdgcn_mfma_f32_16x16x32_bf16(a[mi], b[ni], acc[mi][ni], 0, 0, 0);
            __syncthreads();
        }
        #pragma unroll
        for (int mi = 0; mi < 2; mi++) {
            #pragma unroll
            for (int ni = 0; ni < 2; ni++) {
                int n = n0 + wc * 32 + ni * 16 + ln;
                float bcv = bcPad[n];
                #pragma unroll
                for (int reg = 0; reg < 4; reg++) {
                    int cr = m0 + wr * 32 + mi * 16 + lq * 4 + reg;
                    candbf[cr * 320 + n] = f2bf(sigmoidf_fast(acc[mi][ni][reg] + bcv));
                }
            }
        }
    } else {
        // ---- gate P GEMMs (32 blocks): 64c x 64b-half each
        short* As0 = (short*)smem;              // [64][40]
        short* As1 = (short*)(smem + 5120);
        short* Bs0 = (short*)(smem + 10240);    // [64][40] x3
        short* Bs1 = (short*)(smem + 15360);
        short* Bs2 = (short*)(smem + 20480);
        const int pid = bid - 80;
        const int c0 = (pid >> 1) * 64;
        const int bh = (pid & 1) * 64;
        f32x4_t accR[4], accS[4], accV[4];
        #pragma unroll
        for (int i = 0; i < 4; i++) {
            accR[i] = (f32x4_t){0.f, 0.f, 0.f, 0.f};
            accS[i] = (f32x4_t){0.f, 0.f, 0.f, 0.f};
            accV[i] = (f32x4_t){0.f, 0.f, 0.f, 0.f};
        }
        for (int kk = 0; kk < 320; kk += 32) {
            #pragma unroll
            for (int i = tid; i < 512; i += 256) {   // A: slot(mat0), value(mat1)
                int mat = i >> 8, r2 = i & 255;
                int row = r2 >> 2, q = r2 & 3;
                short* dst = mat ? As1 : As0;
                *(uint4*)(&dst[row * 40 + q * 8]) =
                    *(const uint4*)(catsv + (c0 + row) * 640 + mat * 320 + kk + q * 8);
            }
            #pragma unroll
            for (int i = tid; i < 768; i += 256) {   // B: sys, confs, confv (64 b's)
                int mat = i >> 8, r2 = i & 255;
                int row = r2 >> 2, q = r2 & 3;
                const unsigned short* src = (mat == 0) ? sysB : ((mat == 1) ? confsB : confvB);
                short* dst = (mat == 0) ? Bs0 : ((mat == 1) ? Bs1 : Bs2);
                *(uint4*)(&dst[row * 40 + q * 8]) =
                    *(const uint4*)(src + (bh + row) * 320 + kk + q * 8);
            }
            __syncthreads();
            bf16x8_t aS = *(const bf16x8_t*)(&As0[(w * 16 + ln) * 40 + lq * 8]);
            bf16x8_t aV = *(const bf16x8_t*)(&As1[(w * 16 + ln) * 40 + lq * 8]);
            #pragma unroll
            for (int ni = 0; ni < 4; ni++) {
                bf16x8_t bR = *(const bf16x8_t*)(&Bs0[(ni * 16 + ln) * 40 + lq * 8]);
                bf16x8_t bS = *(const bf16x8_t*)(&Bs1[(ni * 16 + ln) * 40 + lq * 8]);
                bf16x8_t bV = *(const bf16x8_t*)(&Bs2[(ni * 16 + ln) * 40 + lq * 8]);
                accR[ni] = __builtin_amdgcn_mfma_f32_16x16x32_bf16(aS, bR, accR[ni], 0, 0, 0);
                accS[ni] = __builtin_amdgcn_mfma_f32_16x16x32_bf16(aS, bS, accS[ni], 0, 0, 0);
                accV[ni] = __builtin_amdgcn_mfma_f32_16x16x32_bf16(aV, bV, accV[ni], 0, 0, 0);
            }
            __syncthreads();
        }
        #pragma unroll
        for (int ni = 0; ni < 4; ni++) {
            int b = bh + ni * 16 + ln;
            #pragma unroll
            for (int reg = 0; reg < 4; reg++) {
                int c = c0 + w * 16 + lq * 4 + reg;
                Prbf[c * 128 + b] = f2bf(accR[ni][reg]);
                Pcbf[c * 128 + b] = f2bf(accS[ni][reg] * accV[ni][reg]);
            }
        }
    }
}

// ------------------------------------- K2: tap-combine + relu + maxpool -> fu
__global__ __launch_bounds__(64) void combine_kernel(const unsigned short* __restrict__ Pbf,
        const float* __restrict__ b1, const float* __restrict__ b2,
        const float* __restrict__ b3, unsigned short* __restrict__ fubf,
        unsigned short* __restrict__ fubfT) {
    int b = blockIdx.x;
    int f = blockIdx.y * 64 + threadIdx.x;       // 0..319
    if (f >= 300) { fubf[b * 320 + f] = 0; fubfT[f * 128 + b] = 0; return; }
    const unsigned short* base = Pbf + (size_t)b * 40 * 1920;
    float m1 = -1e30f, m2 = -1e30f, m3 = -1e30f;
    float p1prev = 0.f, p3prev = 0.f, p3prev2 = 0.f, p4prev = 0.f;
    for (int t = 0; t < 40; ++t) {
        const unsigned short* r = base + t * 1920;
        float p0 = bf2f(r[f]);
        float p1 = bf2f(r[320 + f]);
        float p2 = bf2f(r[640 + f]);
        float p3 = bf2f(r[960 + f]);
        float p4 = bf2f(r[1280 + f]);
        float p5 = bf2f(r[1600 + f]);
        m1 = fmaxf(m1, p0);
        if (t >= 1) m2 = fmaxf(m2, p1prev + p2);
        if (t >= 2) m3 = fmaxf(m3, p3prev2 + p4prev + p5);
        p3prev2 = p3prev; p3prev = p3; p4prev = p4; p1prev = p1;
    }
    float r = fmaxf(m1 + b1[f], 0.f) + fmaxf(m2 + b2[f], 0.f) + fmaxf(m3 + b3[f], 0.f);
    unsigned short rb = f2bf(r);
    fubf[b * 320 + f]  = rb;
    fubfT[f * 128 + b] = rb;
}

// ------------------------------- K3: m-gate GEMMs + sigmoid: sm = sigmoid(P @ fu)
__global__ __launch_bounds__(256) void mgate_gemm(const unsigned short* __restrict__ Prbf,
        const unsigned short* __restrict__ Pcbf, const unsigned short* __restrict__ fubfT,
        unsigned short* __restrict__ smrbf, unsigned short* __restrict__ smcbf) {
    __shared__ __attribute__((aligned(16))) short As[2][64 * 40];
    __shared__ __attribute__((aligned(16))) short Bs[64 * 40];
    const int tid = threadIdx.x;
    const int m0 = blockIdx.x * 64, n0 = blockIdx.y * 64;
    const int lane = tid & 63, w = tid >> 6;
    const int wr = w & 1, wc = w >> 1;
    const int ln = lane & 15, lq = lane >> 4;
    f32x4_t accR[2][2], accC[2][2];
    #pragma unroll
    for (int i = 0; i < 2; i++)
        #pragma unroll
        for (int j = 0; j < 2; j++) {
            accR[i][j] = (f32x4_t){0.f, 0.f, 0.f, 0.f};
            accC[i][j] = (f32x4_t){0.f, 0.f, 0.f, 0.f};
        }
    for (int kk = 0; kk < 128; kk += 32) {
        #pragma unroll
        for (int i = tid; i < 512; i += 256) {
            int mat = i >> 8, r2 = i & 255;
            int row = r2 >> 2, q = r2 & 3;
            const unsigned short* src = mat ? Pcbf : Prbf;
            *(uint4*)(&As[mat][row * 40 + q * 8]) =
                *(const uint4*)(src + (m0 + row) * 128 + kk + q * 8);
        }
        if (tid < 256) {
            int row = tid >> 2, q = tid & 3;
            *(uint4*)(&Bs[row * 40 + q * 8]) =
                *(const uint4*)(fubfT + (n0 + row) * 128 + kk + q * 8);
        }
        __syncthreads();
        bf16x8_t aR[2], aC[2], b[2];
        #pragma unroll
        for (int mi = 0; mi < 2; mi++) {
            aR[mi] = *(const bf16x8_t*)(&As[0][(wr * 32 + mi * 16 + ln) * 40 + lq * 8]);
            aC[mi] = *(const bf16x8_t*)(&As[1][(wr * 32 + mi * 16 + ln) * 40 + lq * 8]);
        }
        #pragma unroll
        for (int ni = 0; ni < 2; ni++)
            b[ni] = *(const bf16x8_t*)(&Bs[(wc * 32 + ni * 16 + ln) * 40 + lq * 8]);
        #pragma unroll
        for (int mi = 0; mi < 2; mi++)
            #pragma unroll
            for (int ni = 0; ni < 2; ni++) {
                accR[mi][ni] = __builtin_amdgcn_mfma_f32_16x16x32_bf16(aR[mi], b[ni], accR[mi][ni], 0, 0, 0);
                accC[mi][ni] = __builtin_amdgcn_mfma_f32_16x16x32_bf16(aC[mi], b[ni], accC[mi][ni], 0, 0, 0);
            }
        __syncthreads();
    }
    #pragma unroll
    for (int mi = 0; mi < 2; mi++) {
        #pragma unroll
        for (int ni = 0; ni < 2; ni++) {
            int f = n0 + wc * 32 + ni * 16 + ln;
            #pragma unroll
            for (int reg = 0; reg < 4; reg++) {
                int c = m0 + wr * 32 + mi * 16 + lq * 4 + reg;
                smrbf[c * 320 + f] = f2bf(sigmoidf_fast(accR[mi][ni][reg]));
                smcbf[c * 320 + f] = f2bf(sigmoidf_fast(accC[mi][ni][reg]));
            }
        }
    }
}

// ------------------------------- K4: H-layer + joint -> y23[c]
__global__ __launch_bounds__(256) void ygate_gemm(const unsigned short* __restrict__ smrbf,
        const unsigned short* __restrict__ smcbf, const unsigned short* __restrict__ WmrFrag,
        const unsigned short* __restrict__ WmcFrag, const float* __restrict__ bmrPad,
        const float* __restrict__ bmcPad, const float* __restrict__ WjPad,
        const float* __restrict__ bj, float* __restrict__ y23) {
    __shared__ __attribute__((aligned(16))) short As[2][64 * 40];
    __shared__ __attribute__((aligned(16))) short Bs[2][3584];
    const int tid = threadIdx.x;
    const int c0 = blockIdx.x * 64;
    const int lane = tid & 63, w = tid >> 6;
    const int ln = lane & 15, lq = lane >> 4;
    f32x4_t accR[7], accC[7];
    #pragma unroll
    for (int i = 0; i < 7; i++) {
        accR[i] = (f32x4_t){0.f, 0.f, 0.f, 0.f};
        accC[i] = (f32x4_t){0.f, 0.f, 0.f, 0.f};
    }
    for (int kt = 0; kt < 10; kt++) {
        int kk = kt * 32;
        #pragma unroll
        for (int i = tid; i < 512; i += 256) {
            int mat = i >> 8, r2 = i & 255;
            int row = r2 >> 2, q = r2 & 3;
            const unsigned short* src = mat ? smcbf : smrbf;
            *(uint4*)(&As[mat][row * 40 + q * 8]) =
                *(const uint4*)(src + (c0 + row) * 320 + kk + q * 8);
        }
        #pragma unroll
        for (int i = tid; i < 896; i += 256) {
            int mat = i / 448, j = i - mat * 448;
            const uint4* s = (const uint4*)((mat ? WmcFrag : WmrFrag) + kt * 3584);
            ((uint4*)&Bs[mat][0])[j] = s[j];
        }
        __syncthreads();
        bf16x8_t aR = *(const bf16x8_t*)(&As[0][(w * 16 + ln) * 40 + lq * 8]);
        bf16x8_t aC = *(const bf16x8_t*)(&As[1][(w * 16 + ln) * 40 + lq * 8]);
        #pragma unroll
        for (int ni = 0; ni < 7; ni++) {
            bf16x8_t bR = *(const bf16x8_t*)(&Bs[0][(ni * 64 + lane) * 8]);
            bf16x8_t bC = *(const bf16x8_t*)(&Bs[1][(ni * 64 + lane) * 8]);
            accR[ni] = __builtin_amdgcn_mfma_f32_16x16x32_bf16(aR, bR, accR[ni], 0, 0, 0);
            accC[ni] = __builtin_amdgcn_mfma_f32_16x16x32_bf16(aC, bC, accC[ni], 0, 0, 0);
        }
        __syncthreads();
    }
    float psum[4] = {0.f, 0.f, 0.f, 0.f};
    #pragma unroll
    for (int ni = 0; ni < 7; ni++) {
        int n = ni * 16 + ln;
        float wj = WjPad[n], br = bmrPad[n], bcv = bmcPad[n];
        #pragma unroll
        for (int reg = 0; reg < 4; reg++) {
            float hr = sigmoidf_fast(accR[ni][reg] + br);
            float hc = sigmoidf_fast(accC[ni][reg] + bcv);
            psum[reg] += (hr + hc) * wj;
        }
    }
    #pragma unroll
    for (int reg = 0; reg < 4; reg++) {
        float v = psum[reg];
        v += __shfl_xor(v, 1);
        v += __shfl_xor(v, 2);
        v += __shfl_xor(v, 4);
        v += __shfl_xor(v, 8);
        if (ln == 0) {
            int c = c0 + w * 16 + lq * 4 + reg;
            y23[c] = v + 2.0f * bj[0];
        }
    }
}

// --------------------- K5: fused main MLP GEMM (per-c), register A-frag gen
__global__ __launch_bounds__(256) void gemm2_kernel(const unsigned short* __restrict__ candbf,
        const unsigned short* __restrict__ fubf, const unsigned short* __restrict__ WdFrag,
        const float* __restrict__ bdPad, const float* __restrict__ WjPad,
        const float* __restrict__ bj, const float* __restrict__ y23,
        const float* __restrict__ ypast, float* __restrict__ out) {
    __shared__ __attribute__((aligned(16))) short Bs[2][3584];
    __shared__ float bdS[112], WjS[112], ybuf[128];
    const int c = blockIdx.x;
    const int tid = threadIdx.x;
    const int lane = tid & 63, w = tid >> 6;
    const int ln = lane & 15, lq = lane >> 4;
    if (tid < 112) { bdS[tid] = bdPad[tid]; WjS[tid] = WjPad[tid]; }

    const unsigned short* candRow = candbf + c * 320;
    const unsigned short* fuR0 = fubf + (w * 32 + ln) * 320;
    const unsigned short* fuR1 = fuR0 + 16 * 320;

    f32x4_t acc[2][7];
    #pragma unroll
    for (int mi = 0; mi < 2; mi++)
        #pragma unroll
        for (int ni = 0; ni < 7; ni++) acc[mi][ni] = (f32x4_t){0.f, 0.f, 0.f, 0.f};

    {
        const uint4* src = (const uint4*)(WdFrag);
        uint4* dst = (uint4*)&Bs[0][0];
        dst[tid] = src[tid];
        if (tid < 192) dst[tid + 256] = src[tid + 256];
    }
    __syncthreads();

    #pragma unroll
    for (int kt = 0; kt < 10; kt++) {
        if (kt < 9) {
            const uint4* src = (const uint4*)(WdFrag + (kt + 1) * 3584);
            uint4* dst = (uint4*)&Bs[(kt + 1) & 1][0];
            dst[tid] = src[tid];
            if (tid < 192) dst[tid + 256] = src[tid + 256];
        }
        const int k0 = kt * 32 + lq * 8;
        bf16x8_t cf  = *(const bf16x8_t*)(candRow + k0);
        bf16x8_t f0v = *(const bf16x8_t*)(fuR0 + k0);
        bf16x8_t f1v = *(const bf16x8_t*)(fuR1 + k0);
        bf16x8_t a0, a1;
        #pragma unroll
        for (int e = 0; e < 8; e += 2) {
            float cv0 = bf2f((unsigned short)cf[e]);
            float cv1 = bf2f((unsigned short)cf[e + 1]);
            float2 s0 = make_float2(sigmoidf_fast(cv0 * bf2f((unsigned short)f0v[e])),
                                    sigmoidf_fast(cv1 * bf2f((unsigned short)f0v[e + 1])));
            float2 s1 = make_float2(sigmoidf_fast(cv0 * bf2f((unsigned short)f1v[e])),
                                    sigmoidf_fast(cv1 * bf2f((unsigned short)f1v[e + 1])));
            __hip_bfloat162 p0 = __float22bfloat162_rn(s0);
            __hip_bfloat162 p1 = __float22bfloat162_rn(s1);
            ((unsigned int*)&a0)[e >> 1] = *(unsigned int*)&p0;
            ((unsigned int*)&a1)[e >> 1] = *(unsigned int*)&p1;
        }
        #pragma unroll
        for (int ni = 0; ni < 7; ni++) {
            bf16x8_t bfr = *(const bf16x8_t*)(&Bs[kt & 1][(ni * 64 + lane) * 8]);
            acc[0][ni] = __builtin_amdgcn_mfma_f32_16x16x32_bf16(a0, bfr, acc[0][ni], 0, 0, 0);
            acc[1][ni] = __builtin_amdgcn_mfma_f32_16x16x32_bf16(a1, bfr, acc[1][ni], 0, 0, 0);
        }
        __syncthreads();
    }

    float psum[2][4] = {{0.f, 0.f, 0.f, 0.f}, {0.f, 0.f, 0.f, 0.f}};
    #pragma unroll
    for (int mi = 0; mi < 2; mi++) {
        #pragma unroll
        for (int ni = 0; ni < 7; ni++) {
            int n = ni * 16 + ln;
            float bdv = bdS[n], wjv = WjS[n];
            #pragma unroll
            for (int reg = 0; reg < 4; reg++) {
                float h = sigmoidf_fast(acc[mi][ni][reg] + bdv);
                psum[mi][reg] += h * wjv;
            }
        }
    }
    #pragma unroll
    for (int mi = 0; mi < 2; mi++) {
        #pragma unroll
        for (int reg = 0; reg < 4; reg++) {
            float v = psum[mi][reg];
            v += __shfl_xor(v, 1);
            v += __shfl_xor(v, 2);
            v += __shfl_xor(v, 4);
            v += __shfl_xor(v, 8);
            if (ln == 0) ybuf[w * 32 + mi * 16 + lq * 4 + reg] = v;
        }
    }
    __syncthreads();
    if (tid < 128) {
        int b = tid;
        float y1 = ybuf[b] + bj[0];
        out[b * 1000 + c] = 0.5f * (y1 + y23[c]) + 0.5f * ypast[b * 1000 + c];
    }
}

extern "C" void kernel_launch(void* const* d_in, const int* in_sizes, int n_in,
                              void* d_out, int out_size, void* d_ws, size_t ws_size,
                              hipStream_t stream) {
    const float* utt   = (const float*)d_in[0];
    const float* sys   = (const float*)d_in[1];
    const float* confs = (const float*)d_in[2];
    const float* confv = (const float*)d_in[3];
    const float* ypast = (const float*)d_in[4];
    const float* slot  = (const float*)d_in[5];
    const float* value = (const float*)d_in[6];
    const float* Wc    = (const float*)d_in[7];
    const float* bc    = (const float*)d_in[8];
    const float* w1    = (const float*)d_in[9];
    const float* b1    = (const float*)d_in[10];
    const float* w2    = (const float*)d_in[11];
    const float* b2    = (const float*)d_in[12];
    const float* w3    = (const float*)d_in[13];
    const float* b3    = (const float*)d_in[14];
    const float* Wd    = (const float*)d_in[15];
    const float* bd    = (const float*)d_in[16];
    const float* Wmr   = (const float*)d_in[17];
    const float* bmr   = (const float*)d_in[18];
    const float* Wmc   = (const float*)d_in[19];
    const float* bmc   = (const float*)d_in[20];
    const float* Wj    = (const float*)d_in[21];
    const float* bj    = (const float*)d_in[22];

    char* wsb = (char*)d_ws;
    float* y23    = (float*)(wsb + OFF_Y23);
    float* bdPad  = (float*)(wsb + OFF_BDP);
    float* WjPad  = (float*)(wsb + OFF_WJP);
    float* bcPad  = (float*)(wsb + OFF_BCP);
    float* bmrPad = (float*)(wsb + OFF_BMRP);
    float* bmcPad = (float*)(wsb + OFF_BMCP);
    unsigned short* WallTbf = (unsigned short*)(wsb + OFF_WALLT);
    unsigned short* Pbf     = (unsigned short*)(wsb + OFF_PBF);
    unsigned short* fubf    = (unsigned short*)(wsb + OFF_FUBF);
    unsigned short* fubfT   = (unsigned short*)(wsb + OFF_FUBFT);
    unsigned short* catsv   = (unsigned short*)(wsb + OFF_CATSV);
    unsigned short* WcPk    = (unsigned short*)(wsb + OFF_WCPK);
    unsigned short* candbf  = (unsigned short*)(wsb + OFF_CANDBF);
    unsigned short* WdFrag  = (unsigned short*)(wsb + OFF_WDFRAG);
    unsigned short* WmrFrag = (unsigned short*)(wsb + OFF_WMRFRAG);
    unsigned short* WmcFrag = (unsigned short*)(wsb + OFF_WMCFRAG);
    unsigned short* sysB    = (unsigned short*)(wsb + OFF_SYSB);
    unsigned short* confsB  = (unsigned short*)(wsb + OFF_CONFSB);
    unsigned short* confvB  = (unsigned short*)(wsb + OFF_CONFVB);
    unsigned short* Prbf    = (unsigned short*)(wsb + OFF_PRBF);
    unsigned short* Pcbf    = (unsigned short*)(wsb + OFF_PCBF);
    unsigned short* smrbf   = (unsigned short*)(wsb + OFF_SMRBF);
    unsigned short* smcbf   = (unsigned short*)(wsb + OFF_SMCBF);
    unsigned short* Xbf     = (unsigned short*)(wsb + OFF_XBF);
    float* out = (float*)d_out;

    pack_kernel<<<1636, 256, 0, stream>>>(w1, w2, w3, Wc, Wd, Wmr, Wmc, sys, confs, confv,
                                          bd, Wj, bmr, bmc, bc, slot, value, utt,
                                          WallTbf, WdFrag, WmrFrag, WmcFrag,
                                          bdPad, WjPad, bmrPad, bmcPad, bcPad,
                                          sysB, confsB, confvB, catsv, WcPk, Xbf);
    early_kernel<<<1312, 256, 0, stream>>>(Xbf, WallTbf, Pbf,
                                           catsv, WcPk, bcPad, candbf,
                                           sysB, confsB, confvB, Prbf, Pcbf);
    combine_kernel<<<dim3(128, 5), 64, 0, stream>>>(Pbf, b1, b2, b3, fubf, fubfT);
    mgate_gemm<<<dim3(16, 5), 256, 0, stream>>>(Prbf, Pcbf, fubfT, smrbf, smcbf);
    ygate_gemm<<<16, 256, 0, stream>>>(smrbf, smcbf, WmrFrag, WmcFrag,
                                       bmrPad, bmcPad, WjPad, bj, y23);
    gemm2_kernel<<<1000, 256, 0, stream>>>(candbf, fubf, WdFrag, bdPad, WjPad,
                                           bj, y23, ypast, out);
}